// Round 9
// baseline (59.669 us; speedup 1.0000x reference)
//
#include <hip/hip_runtime.h>
#include <hip/hip_bf16.h>
#include <stdint.h>

#define NB 16
#define SLQ 2048
#define SLK 2048
#define DD 64
#define BQ 128
#define BK 64
#define NT (SLK / BK)          // 32 K-tiles
#define QTILES (SLQ / BQ)      // 16 q-tiles per batch
#define LOG2E 1.44269504f

typedef _Float16 f16x8 __attribute__((ext_vector_type(8)));
typedef short s16x8 __attribute__((ext_vector_type(8)));
typedef unsigned int u32x4 __attribute__((ext_vector_type(4)));
typedef unsigned short u16x4 __attribute__((ext_vector_type(4)));
typedef float f32x4 __attribute__((ext_vector_type(4)));
typedef float f32x2 __attribute__((ext_vector_type(2)));
typedef float f32x16 __attribute__((ext_vector_type(16)));

typedef __attribute__((address_space(1))) const void gvoid;
typedef __attribute__((address_space(3))) void lvoid;

__device__ __forceinline__ int swzb(int row, int bytecol) {
    // 128B rows; XOR row bits into byte-bit4..6 to spread banks
    return row * 128 + (bytecol ^ ((row & 7) << 4));
}
// 128-row Q buffer built from two 64-row subtiles
__device__ __forceinline__ int ldsq(int row, int bytecol) {
    return (row >> 6) * 8192 + swzb(row & 63, bytecol);
}

__device__ __forceinline__ void gload16(const void* g, void* l) {
    __builtin_amdgcn_global_load_lds((gvoid*)g, (lvoid*)l, 16, 0, 0);
}
__device__ __forceinline__ void gload4(const void* g, void* l) {
    __builtin_amdgcn_global_load_lds((gvoid*)g, (lvoid*)l, 4, 0, 0);
}

__device__ __forceinline__ uint16_t f2bf(float f) {
    __bf16 h = (__bf16)f;
    return __builtin_bit_cast(uint16_t, h);
}
__device__ __forceinline__ float bf2f(uint16_t u) {
    uint32_t x = ((uint32_t)u) << 16;
    return __builtin_bit_cast(float, x);
}

// sigma: swap bits 2<->3 of the within-16 key index (involution).
__device__ __forceinline__ int sigma16(int x) {
    return (x & ~12) | ((x & 4) << 1) | ((x & 8) >> 1);
}

// exp2 of 16 C-regs -> two bf16 A-frag chunks, NO cross-lane ops.
// Effective key order = sigma (V^T and mask are pre-permuted by sigma in prep).
__device__ __forceinline__ void build_pa(const f32x16& s, s16x8& paA, s16x8& paB) {
    uint32_t w[8];
    #pragma unroll
    for (int i = 0; i < 8; ++i) {
        float p0 = exp2f(s[2 * i]);
        float p1 = exp2f(s[2 * i + 1]);
        w[i] = (uint32_t)f2bf(p0) | ((uint32_t)f2bf(p1) << 16);
    }
    u32x4 wa = {w[0], w[1], w[2], w[3]};
    u32x4 wb = {w[4], w[5], w[6], w[7]};
    paA = __builtin_bit_cast(s16x8, wa);
    paB = __builtin_bit_cast(s16x8, wb);
}

// ---------------- fused prep (unchanged) ----------------
__global__ __launch_bounds__(256)
void prep_all(const float* __restrict__ q, const float* __restrict__ k,
              const float* __restrict__ v, const float* __restrict__ vm,
              char* __restrict__ qs, char* __restrict__ ks,
              char* __restrict__ vts, uint16_t* __restrict__ mb16) {
    const int bid = blockIdx.x;
    if (bid < 1024) {
        const int tl = bid & 511;
        const bool isq = bid < 512;
        const float sc = isq ? LOG2E : 1.0f;
        const float* src = (isq ? q : k) + (size_t)tl * (BK * DD);
        char* dst = (isq ? qs : ks) + (size_t)tl * (BK * DD * 2);
        #pragma unroll
        for (int it = 0; it < 2; ++it) {
            int c = threadIdx.x + it * 256;
            int row = c >> 3, col8 = c & 7;
            f32x4 a  = *(const f32x4*)(src + row * DD + col8 * 8);
            f32x4 b2 = *(const f32x4*)(src + row * DD + col8 * 8 + 4);
            f16x8 h;
            #pragma unroll
            for (int j = 0; j < 4; ++j) {
                h[j] = (_Float16)(a[j] * sc);
                h[4 + j] = (_Float16)(b2[j] * sc);
            }
            *(f16x8*)(dst + swzb(row, col8 * 16)) = h;
        }
    } else if (bid < 1536) {
        const int tl = bid - 1024;               // 0..511, tile of 64 keys
        const float* src = v + (size_t)tl * (BK * DD);
        const float* msk = vm + (size_t)tl * BK;
        char* dst = vts + (size_t)tl * (BK * DD * 2);
        const int d = threadIdx.x & 63;
        #pragma unroll
        for (int it = 0; it < 2; ++it) {
            int key8 = (threadIdx.x >> 6) + it * 4;
            s16x8 h;
            #pragma unroll
            for (int j = 0; j < 8; ++j) {
                int kp = key8 * 8 + j;                       // permuted position
                int sk = (kp & ~15) | sigma16(kp & 15);      // source key
                float mv = msk[sk];
                h[j] = (short)f2bf((mv != 0.f) ? src[sk * DD + d] : 0.f);
            }
            *(s16x8*)(dst + swzb(d, key8 * 16)) = h;
        }
    } else {
        int i = (bid - 1536) * 1024 + threadIdx.x * 4;       // 4-aligned
        f32x4 m = *(const f32x4*)(vm + i);
        u16x4 o;
        #pragma unroll
        for (int j = 0; j < 4; ++j) o[j] = (m[j] != 0.f) ? (uint16_t)0x3F80 : (uint16_t)0;
        int pos = (i & ~15) | sigma16(i & 15);               // still 4-aligned
        *(u16x4*)(mb16 + pos) = o;
    }
}

// ---------------- main: 2-buffer counted-vmcnt pipeline, 4 blocks/CU ----------------
// buffer slot: [K 8KB][V 8KB][mask 256B] = 16640 B; Q staged via bufs[1] in prologue.
// Per-wave vm-ops per STAGE = 5 (4x gload16 + 1x gload4), uniform across waves.
__global__ __launch_bounds__(256, 4)
void attn_fwd(const char* __restrict__ qs, const char* __restrict__ ks,
              const char* __restrict__ vts, const uint16_t* __restrict__ mb16,
              uint16_t* __restrict__ po, float* __restrict__ pl,
              float* __restrict__ out, int nsp)
{
    __shared__ __align__(16) char bufs[2][16640];

    const int tid  = threadIdx.x;
    const int lane = tid & 63;
    const int w    = tid >> 6;       // wave -> 32 q-rows
    const int lh   = lane >> 5;      // half-wave
    const int lr   = lane & 31;

    const int G = 256 * nsp;
    int wg = blockIdx.x;
    wg = (wg & 7) * (G >> 3) + (wg >> 3);      // XCD-chunked swizzle (G % 8 == 0)
    const int qt   = wg & 15;
    const int rest = wg >> 4;
    const int sp   = rest % nsp;
    const int b    = rest / nsp;

    const int qq = NT / nsp, rm = NT % nsp;
    const int t0  = sp * qq + (sp < rm ? sp : rm);
    const int cnt = qq + (sp < rm ? 1 : 0);

    const char* qtile = qs  + (size_t)(b * 32 + qt * 2) * 8192;   // 128 rows = 2 subtiles
    const char* kbase = ks  + (size_t)(b * 32 + t0) * 8192;
    const char* vbase = vts + (size_t)(b * 32 + t0) * 8192;
    const uint16_t* mkbase = mb16 + (size_t)b * SLK + t0 * BK;

#define STAGE(kt, bf) do {                                                      \
        const char* kg_ = kbase + (size_t)(kt) * 8192;                          \
        const char* vg_ = vbase + (size_t)(kt) * 8192;                          \
        _Pragma("unroll")                                                       \
        for (int i_ = 0; i_ < 2; ++i_) {                                        \
            int ch_ = w * 2 + i_;                                               \
            gload16(kg_ + ch_ * 1024 + lane * 16, bufs[bf] + ch_ * 1024);       \
            gload16(vg_ + ch_ * 1024 + lane * 16, bufs[bf] + 8192 + ch_ * 1024);\
        }                                                                       \
        gload4((const char*)(mkbase + (size_t)(kt) * BK) + (lane & 31) * 4,     \
               bufs[bf] + 16384);                                               \
    } while (0)

    // ---- prologue: Q -> bufs[1]; tile 0 -> bufs[0] ----
    #pragma unroll
    for (int i = 0; i < 4; ++i) {
        int ch = w * 4 + i;
        gload16(qtile + ch * 1024 + lane * 16, bufs[1] + ch * 1024);
    }
    STAGE(0, 0);
    asm volatile("s_waitcnt vmcnt(5)" ::: "memory");   // Q landed (tile0 may fly)
    __builtin_amdgcn_s_barrier();

    // Q B-frags: col(q-row) = w*32+lr, k(d) = kd*16 + lh*8 + j
    f16x8 qf[4];
    #pragma unroll
    for (int kd = 0; kd < 4; ++kd)
        qf[kd] = *(const f16x8*)(bufs[1] + ldsq(w * 32 + lr, kd * 32 + lh * 16));
    asm volatile("s_waitcnt lgkmcnt(0)" ::: "memory");   // qf in regs before bufs[1] reuse
    __builtin_amdgcn_s_barrier();

    f32x16 oacc0 = (f32x16)(0.0f), oacc1 = (f32x16)(0.0f), rsacc = (f32x16)(0.0f);

    for (int t = 0; t < cnt; ++t) {
        const int cur = t & 1;
        // 1-deep prefetch with counted wait: tile t complete, tile t+1 in flight.
        if (t + 1 < cnt) {
            STAGE(t + 1, cur ^ 1);
            asm volatile("s_waitcnt vmcnt(5)" ::: "memory");
        } else {
            asm volatile("s_waitcnt vmcnt(0)" ::: "memory");
        }
        __builtin_amdgcn_s_barrier();

        const char* kb_ = bufs[cur];
        const char* vb_ = bufs[cur] + 8192;
        const char* mb_ = bufs[cur] + 16384;

        // two 32-key strips, processed sequentially (halves live registers;
        // strip-1 QK MFMAs can hoist under strip-0 exp2)
        #pragma unroll
        for (int st = 0; st < 2; ++st) {
            f32x16 s = (f32x16)(0.0f);
            __builtin_amdgcn_s_setprio(1);
            #pragma unroll
            for (int kd = 0; kd < 4; ++kd) {
                f16x8 kf = *(const f16x8*)(kb_ + swzb(st * 32 + lr, kd * 32 + lh * 16));
                s = __builtin_amdgcn_mfma_f32_32x32x16_f16(kf, qf[kd], s, 0, 0, 0);
            }
            __builtin_amdgcn_s_setprio(0);

            s16x8 pa0, pa1;
            build_pa(s, pa0, pa1);                     // keys st*32 .. st*32+31 (sigma order)

            s16x8 mf0 = *(const s16x8*)(mb_ + st * 64 + lh * 16);
            s16x8 mf1 = *(const s16x8*)(mb_ + st * 64 + 32 + lh * 16);

            __builtin_amdgcn_s_setprio(1);
            rsacc = __builtin_amdgcn_mfma_f32_32x32x16_bf16(pa0, mf0, rsacc, 0, 0, 0);
            rsacc = __builtin_amdgcn_mfma_f32_32x32x16_bf16(pa1, mf1, rsacc, 0, 0, 0);

            s16x8 vl0 = *(const s16x8*)(vb_ + swzb(lr,      st * 64 + lh * 16));
            s16x8 vh0 = *(const s16x8*)(vb_ + swzb(32 + lr, st * 64 + lh * 16));
            oacc0 = __builtin_amdgcn_mfma_f32_32x32x16_bf16(pa0, vl0, oacc0, 0, 0, 0);
            oacc1 = __builtin_amdgcn_mfma_f32_32x32x16_bf16(pa0, vh0, oacc1, 0, 0, 0);
            s16x8 vl1 = *(const s16x8*)(vb_ + swzb(lr,      st * 64 + 32 + lh * 16));
            s16x8 vh1 = *(const s16x8*)(vb_ + swzb(32 + lr, st * 64 + 32 + lh * 16));
            oacc0 = __builtin_amdgcn_mfma_f32_32x32x16_bf16(pa1, vl1, oacc0, 0, 0, 0);
            oacc1 = __builtin_amdgcn_mfma_f32_32x32x16_bf16(pa1, vh1, oacc1, 0, 0, 0);
            __builtin_amdgcn_s_setprio(0);
        }

        // all LDS reads of this buffer done before any wave re-stages into it
        asm volatile("s_waitcnt lgkmcnt(0)" ::: "memory");
        __builtin_amdgcn_s_barrier();
    }
#undef STAGE

    // ---- epilogue: q-row = w*32 + (r&3)+8*(r>>2)+4*lh, d = lr / 32+lr ----
    if (nsp == 1) {
        float* ob = out + ((size_t)b * SLQ + (size_t)qt * BQ) * DD;
        #pragma unroll
        for (int r = 0; r < 16; ++r) {
            int row = w * 32 + (r & 3) + 8 * (r >> 2) + 4 * lh;
            float inv = 1.f / (rsacc[r] + 1e-13f);
            ob[row * DD + lr]      = oacc0[r] * inv;
            ob[row * DD + 32 + lr] = oacc1[r] * inv;
        }
    } else {
        uint16_t* pob = po + (size_t)wg * (BQ * DD);
        #pragma unroll
        for (int r = 0; r < 16; ++r) {
            int row = w * 32 + (r & 3) + 8 * (r >> 2) + 4 * lh;
            pob[row * DD + lr]      = f2bf(oacc0[r]);
            pob[row * DD + 32 + lr] = f2bf(oacc1[r]);
            if (lr == 0) pl[(size_t)wg * BQ + row] = rsacc[r];
        }
    }
}

// ---------------- merge: out = (Σ O_s) / (Σ l_s + eps), bf16 partials ----------------
__global__ __launch_bounds__(256)
void merge_k(const uint16_t* __restrict__ po, const float* __restrict__ pl,
             float* __restrict__ out, int nsp) {
    const int t  = blockIdx.x;        // 0..255 q-tiles
    const int b  = t >> 4, qt = t & 15;
    const int i0 = (b * nsp) * 16 + qt;
    const int r0 = threadIdx.x >> 4;
    const int c4 = (threadIdx.x & 15) * 4;
    float* ob = out + ((size_t)b * SLQ + (size_t)qt * BQ) * DD;
    for (int rr = 0; rr < BQ; rr += 16) {
        int r = r0 + rr;
        float l = 1e-13f;
        f32x4 acc = (f32x4){0.f, 0.f, 0.f, 0.f};
        for (int s = 0; s < nsp; ++s) {
            int idx = i0 + s * 16;
            l += pl[(size_t)idx * BQ + r];
            u16x4 a = *(const u16x4*)(po + (size_t)idx * (BQ * DD) + r * DD + c4);
            #pragma unroll
            for (int j = 0; j < 4; ++j) acc[j] += bf2f(a[j]);
        }
        float inv = 1.f / l;
        f32x4 o;
        #pragma unroll
        for (int j = 0; j < 4; ++j) o[j] = acc[j] * inv;
        *(f32x4*)(ob + r * DD + c4) = o;
    }
}

// ---------------- fallback (round-2 proven kernel, used if ws too small) ----------------
__global__ __launch_bounds__(256, 2)
void attn_fallback(const float* __restrict__ q, const float* __restrict__ k,
                   const float* __restrict__ v, const float* __restrict__ vm,
                   float* __restrict__ out)
{
    __shared__ __align__(16) char lqh[64 * DD * 2];
    __shared__ __align__(16) char lql[64 * DD * 2];
    __shared__ __align__(16) char lkh[BK * DD * 2];
    __shared__ __align__(16) char lkl[BK * DD * 2];
    __shared__ __align__(16) char lvt[DD * BK * 2];
    __shared__ __align__(16) char lpp[64 * BK * 2];
    __shared__ float lmask[BK];

    const int tid  = threadIdx.x;
    const int lane = tid & 63;
    const int w    = tid >> 6;
    const int lg   = lane >> 4;
    const int lm   = lane & 15;

    const int b  = blockIdx.y;
    const int qt = blockIdx.x;

    const float* qb = q + ((size_t)b * SLQ + (size_t)qt * 64) * DD;
    const float* kb = k + (size_t)b * SLK * DD;
    const float* vb = v + (size_t)b * SLK * DD;
    const float* mb = vm + (size_t)b * SLK;

    #pragma unroll
    for (int it = 0; it < 2; ++it) {
        int c = tid + it * 256;
        int row = c >> 3, col8 = c & 7;
        f32x4 a  = *(const f32x4*)(qb + row * DD + col8 * 8);
        f32x4 bb = *(const f32x4*)(qb + row * DD + col8 * 8 + 4);
        s16x8 h, l;
        #pragma unroll
        for (int j = 0; j < 4; ++j) {
            uint16_t hh = f2bf(a[j]);
            h[j] = (short)hh; l[j] = (short)f2bf(a[j] - bf2f(hh));
            uint16_t hb = f2bf(bb[j]);
            h[4 + j] = (short)hb; l[4 + j] = (short)f2bf(bb[j] - bf2f(hb));
        }
        *(s16x8*)(lqh + swzb(row, col8 * 16)) = h;
        *(s16x8*)(lql + swzb(row, col8 * 16)) = l;
    }
    __syncthreads();

    s16x8 qfh[2], qfl[2];
    #pragma unroll
    for (int kc = 0; kc < 2; ++kc) {
        qfh[kc] = *(const s16x8*)(lqh + swzb(w * 16 + lm, kc * 64 + lg * 16));
        qfl[kc] = *(const s16x8*)(lql + swzb(w * 16 + lm, kc * 64 + lg * 16));
    }

    float mrow[4], lrow[4];
    f32x4 oacc[4];
    #pragma unroll
    for (int i = 0; i < 4; ++i) { mrow[i] = -1e30f; lrow[i] = 0.f; }
    #pragma unroll
    for (int d = 0; d < 4; ++d) oacc[d] = (f32x4){0.f, 0.f, 0.f, 0.f};

    for (int kt = 0; kt < NT; ++kt) {
        __syncthreads();
        const float* ks2 = kb + (size_t)kt * BK * DD;
        const float* vs = vb + (size_t)kt * BK * DD;

        #pragma unroll
        for (int it = 0; it < 2; ++it) {
            int c = tid + it * 256;
            int row = c >> 3, col8 = c & 7;
            f32x4 a  = *(const f32x4*)(ks2 + row * DD + col8 * 8);
            f32x4 bb = *(const f32x4*)(ks2 + row * DD + col8 * 8 + 4);
            s16x8 h, l;
            #pragma unroll
            for (int j = 0; j < 4; ++j) {
                uint16_t hh = f2bf(a[j]);
                h[j] = (short)hh; l[j] = (short)f2bf(a[j] - bf2f(hh));
                uint16_t hb = f2bf(bb[j]);
                h[4 + j] = (short)hb; l[4 + j] = (short)f2bf(bb[j] - bf2f(hb));
            }
            *(s16x8*)(lkh + swzb(row, col8 * 16)) = h;
            *(s16x8*)(lkl + swzb(row, col8 * 16)) = l;
        }
        #pragma unroll
        for (int it = 0; it < 8; ++it) {
            int c = tid + it * 256;
            int key = c >> 5, dp = (c & 31) * 2;
            f32x2 a = *(const f32x2*)(vs + key * DD + dp);
            *(uint16_t*)(lvt + swzb(dp,     key * 2)) = f2bf(a[0]);
            *(uint16_t*)(lvt + swzb(dp + 1, key * 2)) = f2bf(a[1]);
        }
        if (tid < BK) lmask[tid] = mb[kt * BK + tid];
        __syncthreads();

        f32x4 s[4];
        #pragma unroll
        for (int f = 0; f < 4; ++f) s[f] = (f32x4){0.f, 0.f, 0.f, 0.f};
        #pragma unroll
        for (int f = 0; f < 4; ++f) {
            #pragma unroll
            for (int kc = 0; kc < 2; ++kc) {
                s16x8 kfh = *(const s16x8*)(lkh + swzb(f * 16 + lm, kc * 64 + lg * 16));
                s16x8 kfl = *(const s16x8*)(lkl + swzb(f * 16 + lm, kc * 64 + lg * 16));
                s[f] = __builtin_amdgcn_mfma_f32_16x16x32_bf16(qfh[kc], kfh, s[f], 0, 0, 0);
                s[f] = __builtin_amdgcn_mfma_f32_16x16x32_bf16(qfh[kc], kfl, s[f], 0, 0, 0);
                s[f] = __builtin_amdgcn_mfma_f32_16x16x32_bf16(qfl[kc], kfh, s[f], 0, 0, 0);
            }
        }

        float mv[4];
        #pragma unroll
        for (int f = 0; f < 4; ++f) mv[f] = lmask[f * 16 + lm];

        float pmax[4];
        #pragma unroll
        for (int i = 0; i < 4; ++i) {
            float x = -1e30f;
            #pragma unroll
            for (int f = 0; f < 4; ++f) {
                float sv = (mv[f] != 0.f) ? s[f][i] : -1e30f;
                s[f][i] = sv;
                x = fmaxf(x, sv);
            }
            #pragma unroll
            for (int off = 1; off < 16; off <<= 1)
                x = fmaxf(x, __shfl_xor(x, off, 64));
            pmax[i] = x;
        }

        float scl[4];
        #pragma unroll
        for (int i = 0; i < 4; ++i) {
            float mn = fmaxf(mrow[i], pmax[i]);
            scl[i] = __expf(mrow[i] - mn);
            mrow[i] = mn;
        }
        float rs[4] = {0.f, 0.f, 0.f, 0.f};
        #pragma unroll
        for (int f = 0; f < 4; ++f) {
            #pragma unroll
            for (int i = 0; i < 4; ++i) {
                float p = __expf(s[f][i] - mrow[i]);
                s[f][i] = p;
                rs[i] += p;
            }
        }
        #pragma unroll
        for (int i = 0; i < 4; ++i) {
            #pragma unroll
            for (int off = 1; off < 16; off <<= 1)
                rs[i] += __shfl_xor(rs[i], off, 64);
            lrow[i] = lrow[i] * scl[i] + rs[i];
        }
        #pragma unroll
        for (int d = 0; d < 4; ++d)
            #pragma unroll
            for (int i = 0; i < 4; ++i)
                oacc[d][i] *= scl[i];

        #pragma unroll
        for (int f = 0; f < 4; ++f)
            #pragma unroll
            for (int i = 0; i < 4; ++i)
                *(uint16_t*)(lpp + swzb(w * 16 + lg * 4 + i, (f * 16 + lm) * 2)) = f2bf(s[f][i]);
        __syncthreads();

        #pragma unroll
        for (int kc = 0; kc < 2; ++kc) {
            s16x8 pf = *(const s16x8*)(lpp + swzb(w * 16 + lm, kc * 64 + lg * 16));
            #pragma unroll
            for (int d = 0; d < 4; ++d) {
                s16x8 vf = *(const s16x8*)(lvt + swzb(d * 16 + lm, kc * 64 + lg * 16));
                oacc[d] = __builtin_amdgcn_mfma_f32_16x16x32_bf16(pf, vf, oacc[d], 0, 0, 0);
            }
        }
    }

    float* ob = out + ((size_t)b * SLQ + (size_t)qt * 64) * DD;
    #pragma unroll
    for (int i = 0; i < 4; ++i) {
        float inv = 1.f / (lrow[i] + 1e-13f);
        int row = w * 16 + lg * 4 + i;
        #pragma unroll
        for (int d = 0; d < 4; ++d)
            ob[row * DD + d * 16 + lm] = oacc[d][i] * inv;
    }
}

extern "C" void kernel_launch(void* const* d_in, const int* in_sizes, int n_in,
                              void* d_out, int out_size, void* d_ws, size_t ws_size,
                              hipStream_t stream) {
    const float* q  = (const float*)d_in[0];
    const float* k  = (const float*)d_in[1];
    const float* v  = (const float*)d_in[2];
    const float* vm = (const float*)d_in[3];
    float* out = (float*)d_out;

    const size_t TB     = (size_t)NB * SLK * DD * 2;      // 4 MB per fp16/bf16 tensor
    const size_t MB     = (size_t)NB * SLK * 2;           // 64 KB bf16 mask
    const size_t PL_PER = (size_t)NB * QTILES * BQ * 4;       // 128 KB per split-unit
    const size_t PO_PER = (size_t)NB * QTILES * BQ * DD * 2;  // 4 MB per split-unit (bf16)
    const size_t base = 3 * TB + MB;

    int nsp = 0;
    for (int c = 4; c >= 1; --c) {
        if (ws_size >= base + (size_t)c * (PL_PER + PO_PER)) { nsp = c; break; }
    }
    if (nsp == 0) {
        if (ws_size >= base) nsp = 1;   // nsp=1 needs no po/pl
        else {
            dim3 grid(SLQ / 64, NB);
            attn_fallback<<<grid, dim3(256), 0, stream>>>(q, k, v, vm, out);
            return;
        }
    }

    char*     qs   = (char*)d_ws;
    char*     ks   = qs + TB;
    char*     vts  = ks + TB;
    uint16_t* mb16 = (uint16_t*)(vts + TB);
    float*    pl   = (float*)((char*)mb16 + MB);
    uint16_t* po   = (uint16_t*)((char*)pl + (size_t)nsp * PL_PER);

    prep_all<<<dim3(1568), dim3(256), 0, stream>>>(q, k, v, vm, qs, ks, vts, mb16);
    attn_fwd<<<dim3(256 * nsp), dim3(256), 0, stream>>>(qs, ks, vts, mb16, po, pl, out, nsp);
    if (nsp > 1)
        merge_k<<<dim3(NB * QTILES), dim3(256), 0, stream>>>(po, pl, out, nsp);
}

// Round 11
// 49.145 us; speedup vs baseline: 1.2141x; 1.2141x over previous
//
#include <hip/hip_runtime.h>
#include <hip/hip_bf16.h>
#include <stdint.h>

#define NB 16
#define SLQ 2048
#define SLK 2048
#define DD 64
#define BQ 64
#define BK 64
#define NT (SLK / BK)          // 32 K-tiles
#define QTILES (SLQ / BQ)      // 32 q-tiles per batch
#define LOG2E 1.44269504f

typedef _Float16 f16x8 __attribute__((ext_vector_type(8)));
typedef short s16x8 __attribute__((ext_vector_type(8)));
typedef unsigned short u16x4 __attribute__((ext_vector_type(4)));
typedef float f32x4 __attribute__((ext_vector_type(4)));
typedef float f32x2 __attribute__((ext_vector_type(2)));

typedef __attribute__((address_space(1))) const void gvoid;
typedef __attribute__((address_space(3))) void lvoid;

__device__ __forceinline__ int swzb(int row, int bytecol) {
    // 128B rows; XOR row bits into byte-bit4..6 to spread banks
    return row * 128 + (bytecol ^ ((row & 7) << 4));
}

__device__ __forceinline__ void gload16(const void* g, void* l) {
    __builtin_amdgcn_global_load_lds((gvoid*)g, (lvoid*)l, 16, 0, 0);
}

__device__ __forceinline__ uint16_t f2bf(float f) {
    __bf16 h = (__bf16)f;
    return __builtin_bit_cast(uint16_t, h);
}
__device__ __forceinline__ float bf2f(uint16_t u) {
    uint32_t x = ((uint32_t)u) << 16;
    return __builtin_bit_cast(float, x);
}

// ---------------- fused prep ----------------
// blocks 0..511: Q (f32 -> fp16 * LOG2E), 512..1023: K (fp16),
// 1024..1535: V (f32 -> bf16, transposed [d][key]), 1536..1663: mask -> bias f32
__global__ __launch_bounds__(256)
void prep_all(const float* __restrict__ q, const float* __restrict__ k,
              const float* __restrict__ v, const float* __restrict__ vm,
              char* __restrict__ qs, char* __restrict__ ks,
              char* __restrict__ vts, float* __restrict__ bias2) {
    const int bid = blockIdx.x;
    if (bid < 1024) {
        const int tl = bid & 511;
        const bool isq = bid < 512;
        const float sc = isq ? LOG2E : 1.0f;
        const float* src = (isq ? q : k) + (size_t)tl * (BK * DD);
        char* dst = (isq ? qs : ks) + (size_t)tl * (BK * DD * 2);
        #pragma unroll
        for (int it = 0; it < 2; ++it) {
            int c = threadIdx.x + it * 256;
            int row = c >> 3, col8 = c & 7;
            f32x4 a  = *(const f32x4*)(src + row * DD + col8 * 8);
            f32x4 b2 = *(const f32x4*)(src + row * DD + col8 * 8 + 4);
            f16x8 h;
            #pragma unroll
            for (int j = 0; j < 4; ++j) {
                h[j] = (_Float16)(a[j] * sc);
                h[4 + j] = (_Float16)(b2[j] * sc);
            }
            *(f16x8*)(dst + swzb(row, col8 * 16)) = h;
        }
    } else if (bid < 1536) {
        const int tl = bid - 1024;               // 0..511
        const float* src = v + (size_t)tl * (BK * DD);
        char* dst = vts + (size_t)tl * (BK * DD * 2);
        const int d = threadIdx.x & 63;
        #pragma unroll
        for (int it = 0; it < 2; ++it) {
            int key8 = (threadIdx.x >> 6) + it * 4;  // 0..7
            s16x8 h;
            #pragma unroll
            for (int j = 0; j < 8; ++j)
                h[j] = (short)f2bf(src[(key8 * 8 + j) * DD + d]);
            *(s16x8*)(dst + swzb(d, key8 * 16)) = h;
        }
    } else {
        int i = (bid - 1536) * 256 + threadIdx.x;
        bias2[i] = (vm[i] != 0.f) ? 0.f : -2e30f;
    }
}

// ---------------- main flash-attn (round-4 champion structure, exp2) ----------------
// 16x16x32 MFMA, no-max unnormalized softmax, P via wave-private LDS.
__global__ __launch_bounds__(256, 4)
void attn_fwd(const char* __restrict__ qs, const char* __restrict__ ks,
              const char* __restrict__ vts, const float* __restrict__ bias2,
              uint16_t* __restrict__ po, float* __restrict__ pl,
              float* __restrict__ out, int nsp)
{
    __shared__ __align__(16) char lp[BQ * DD * 2];        // Q stage (fp16), then P (bf16)
    __shared__ __align__(16) char lk[2][BK * DD * 2];     // K fp16 [key][d]
    __shared__ __align__(16) char lv[2][BK * DD * 2];     // V^T bf16 [d][key]

    const int tid  = threadIdx.x;
    const int lane = tid & 63;
    const int w    = tid >> 6;       // wave -> 16 q-rows
    const int lg   = lane >> 4;      // lane group 0..3
    const int lm   = lane & 15;

    const int G = 512 * nsp;
    int wg = blockIdx.x;
    wg = (wg & 7) * (G >> 3) + (wg >> 3);      // XCD-chunked swizzle (G % 8 == 0)
    const int qt   = wg & 31;
    const int rest = wg >> 5;
    const int sp   = rest % nsp;
    const int b    = rest / nsp;

    const int qq = NT / nsp, rm = NT % nsp;
    const int t0  = sp * qq + (sp < rm ? sp : rm);
    const int cnt = qq + (sp < rm ? 1 : 0);

    const char* qtile = qs  + (size_t)(b * 32 + qt) * 8192;
    const char* kbase = ks  + (size_t)(b * 32 + t0) * 8192;
    const char* vbase = vts + (size_t)(b * 32 + t0) * 8192;
    const float* mbias = bias2 + (size_t)b * SLK + t0 * BK;

    // prologue: stage Q (into lp) + tile 0 K/V
    #pragma unroll
    for (int i = 0; i < 2; ++i) {
        int ch = w * 2 + i;
        gload16(qtile + ch * 1024 + lane * 16, lp + ch * 1024);
    }
    #pragma unroll
    for (int i = 0; i < 2; ++i) {
        int ch = w * 2 + i;
        gload16(kbase + ch * 1024 + lane * 16, lk[0] + ch * 1024);
        gload16(vbase + ch * 1024 + lane * 16, lv[0] + ch * 1024);
    }
    asm volatile("s_waitcnt vmcnt(0)" ::: "memory");
    __syncthreads();

    // Q A-frags: row = lm (q-row within wave strip), k(d) = kc*32 + lg*8 + j
    f16x8 qf[2];
    #pragma unroll
    for (int kc = 0; kc < 2; ++kc)
        qf[kc] = *(const f16x8*)(lp + swzb(w * 16 + lm, kc * 64 + lg * 16));

    s16x8 ones;
    #pragma unroll
    for (int j = 0; j < 8; ++j) ones[j] = (short)0x3F80;   // bf16 1.0

    f32x4 oacc[4], rsacc;
    #pragma unroll
    for (int d = 0; d < 4; ++d) oacc[d] = (f32x4){0.f, 0.f, 0.f, 0.f};
    rsacc = (f32x4){0.f, 0.f, 0.f, 0.f};

    int buf = 0;
    for (int kt = 0; kt < cnt; ++kt) {
        // bias loads FIRST (older vmcnt entries than prefetch)
        float bv[4];
        #pragma unroll
        for (int f = 0; f < 4; ++f) bv[f] = mbias[kt * BK + f * 16 + lm];

        // prefetch next tile into other buffer
        if (kt + 1 < cnt) {
            const char* kg = kbase + (size_t)(kt + 1) * 8192;
            const char* vg = vbase + (size_t)(kt + 1) * 8192;
            #pragma unroll
            for (int i = 0; i < 2; ++i) {
                int ch = w * 2 + i;
                gload16(kg + ch * 1024 + lane * 16, lk[buf ^ 1] + ch * 1024);
                gload16(vg + ch * 1024 + lane * 16, lv[buf ^ 1] + ch * 1024);
            }
        }

        // ---- S = Q K^T (fp16): D[qrow=lg*4+i][key=f*16+lm] ----
        f32x4 s[4];
        #pragma unroll
        for (int f = 0; f < 4; ++f) s[f] = (f32x4){0.f, 0.f, 0.f, 0.f};
        #pragma unroll
        for (int f = 0; f < 4; ++f) {
            #pragma unroll
            for (int kc = 0; kc < 2; ++kc) {
                f16x8 kf = *(const f16x8*)(lk[buf] + swzb(f * 16 + lm, kc * 64 + lg * 16));
                s[f] = __builtin_amdgcn_mfma_f32_16x16x32_f16(qf[kc], kf, s[f], 0, 0, 0);
            }
        }

        // ---- p = exp2(s + bias), unnormalized; write P (bf16) to LDS ----
        #pragma unroll
        for (int f = 0; f < 4; ++f) {
            #pragma unroll
            for (int i = 0; i < 4; ++i) {
                float p = __builtin_amdgcn_exp2f(s[f][i] + bv[f]);
                *(uint16_t*)(lp + swzb(w * 16 + lg * 4 + i, (f * 16 + lm) * 2)) = f2bf(p);
            }
        }

        // ---- O += P V, rowsum += P * ones (bf16) ----
        #pragma unroll
        for (int kc = 0; kc < 2; ++kc) {
            s16x8 pf = *(const s16x8*)(lp + swzb(w * 16 + lm, kc * 64 + lg * 16));
            rsacc = __builtin_amdgcn_mfma_f32_16x16x32_bf16(pf, ones, rsacc, 0, 0, 0);
            #pragma unroll
            for (int d = 0; d < 4; ++d) {
                s16x8 vf = *(const s16x8*)(lv[buf] + swzb(d * 16 + lm, kc * 64 + lg * 16));
                oacc[d] = __builtin_amdgcn_mfma_f32_16x16x32_bf16(pf, vf, oacc[d], 0, 0, 0);
            }
        }

        asm volatile("s_waitcnt vmcnt(0)" ::: "memory");
        __syncthreads();
        buf ^= 1;
    }

    // ---- epilogue ----
    if (nsp == 1) {
        float* ob = out + ((size_t)b * SLQ + (size_t)qt * BQ) * DD;
        #pragma unroll
        for (int i = 0; i < 4; ++i) {
            float inv = 1.f / (rsacc[i] + 1e-13f);
            int row = w * 16 + lg * 4 + i;
            #pragma unroll
            for (int d = 0; d < 4; ++d)
                ob[row * DD + d * 16 + lm] = oacc[d][i] * inv;
        }
    } else {
        uint16_t* pob = po + (size_t)wg * (BQ * DD);
        #pragma unroll
        for (int i = 0; i < 4; ++i) {
            int row = w * 16 + lg * 4 + i;
            #pragma unroll
            for (int d = 0; d < 4; ++d)
                pob[row * DD + d * 16 + lm] = f2bf(oacc[d][i]);
            if (lm == 0) pl[(size_t)wg * BQ + row] = rsacc[i];
        }
    }
}

// ---------------- merge: out = (Σ O_s) / (Σ l_s + eps), bf16 partials ----------------
__global__ __launch_bounds__(256)
void merge_k(const uint16_t* __restrict__ po, const float* __restrict__ pl,
             float* __restrict__ out, int nsp) {
    const int t  = blockIdx.x;        // 0..511 q-tiles
    const int b  = t >> 5, qt = t & 31;
    const int i0 = (b * nsp) * 32 + qt;
    const int r0 = threadIdx.x >> 4;
    const int c4 = (threadIdx.x & 15) * 4;
    float* ob = out + ((size_t)b * SLQ + (size_t)qt * BQ) * DD;
    #pragma unroll
    for (int rr = 0; rr < BQ; rr += 16) {
        int r = r0 + rr;
        float l = 1e-13f;
        f32x4 acc = (f32x4){0.f, 0.f, 0.f, 0.f};
        for (int s = 0; s < nsp; ++s) {
            int idx = i0 + s * 32;
            l += pl[(size_t)idx * BQ + r];
            u16x4 a = *(const u16x4*)(po + (size_t)idx * (BQ * DD) + r * DD + c4);
            #pragma unroll
            for (int j = 0; j < 4; ++j) acc[j] += bf2f(a[j]);
        }
        float inv = 1.f / l;
        f32x4 o;
        #pragma unroll
        for (int j = 0; j < 4; ++j) o[j] = acc[j] * inv;
        *(f32x4*)(ob + r * DD + c4) = o;
    }
}

// ---------------- fallback (round-2 proven kernel, used if ws too small) ----------------
__global__ __launch_bounds__(256, 2)
void attn_fallback(const float* __restrict__ q, const float* __restrict__ k,
                   const float* __restrict__ v, const float* __restrict__ vm,
                   float* __restrict__ out)
{
    __shared__ __align__(16) char lqh[64 * DD * 2];
    __shared__ __align__(16) char lql[64 * DD * 2];
    __shared__ __align__(16) char lkh[BK * DD * 2];
    __shared__ __align__(16) char lkl[BK * DD * 2];
    __shared__ __align__(16) char lvt[DD * BK * 2];
    __shared__ __align__(16) char lpp[64 * BK * 2];
    __shared__ float lmask[BK];

    const int tid  = threadIdx.x;
    const int lane = tid & 63;
    const int w    = tid >> 6;
    const int lg   = lane >> 4;
    const int lm   = lane & 15;

    const int b  = blockIdx.y;
    const int qt = blockIdx.x;

    const float* qb = q + ((size_t)b * SLQ + (size_t)qt * 64) * DD;
    const float* kb = k + (size_t)b * SLK * DD;
    const float* vb = v + (size_t)b * SLK * DD;
    const float* mb = vm + (size_t)b * SLK;

    #pragma unroll
    for (int it = 0; it < 2; ++it) {
        int c = tid + it * 256;
        int row = c >> 3, col8 = c & 7;
        f32x4 a  = *(const f32x4*)(qb + row * DD + col8 * 8);
        f32x4 bb = *(const f32x4*)(qb + row * DD + col8 * 8 + 4);
        s16x8 h, l;
        #pragma unroll
        for (int j = 0; j < 4; ++j) {
            uint16_t hh = f2bf(a[j]);
            h[j] = (short)hh; l[j] = (short)f2bf(a[j] - bf2f(hh));
            uint16_t hb = f2bf(bb[j]);
            h[4 + j] = (short)hb; l[4 + j] = (short)f2bf(bb[j] - bf2f(hb));
        }
        *(s16x8*)(lqh + swzb(row, col8 * 16)) = h;
        *(s16x8*)(lql + swzb(row, col8 * 16)) = l;
    }
    __syncthreads();

    s16x8 qfh[2], qfl[2];
    #pragma unroll
    for (int kc = 0; kc < 2; ++kc) {
        qfh[kc] = *(const s16x8*)(lqh + swzb(w * 16 + lm, kc * 64 + lg * 16));
        qfl[kc] = *(const s16x8*)(lql + swzb(w * 16 + lm, kc * 64 + lg * 16));
    }

    float mrow[4], lrow[4];
    f32x4 oacc[4];
    #pragma unroll
    for (int i = 0; i < 4; ++i) { mrow[i] = -1e30f; lrow[i] = 0.f; }
    #pragma unroll
    for (int d = 0; d < 4; ++d) oacc[d] = (f32x4){0.f, 0.f, 0.f, 0.f};

    for (int kt = 0; kt < NT; ++kt) {
        __syncthreads();
        const float* ks2 = kb + (size_t)kt * BK * DD;
        const float* vs = vb + (size_t)kt * BK * DD;

        #pragma unroll
        for (int it = 0; it < 2; ++it) {
            int c = tid + it * 256;
            int row = c >> 3, col8 = c & 7;
            f32x4 a  = *(const f32x4*)(ks2 + row * DD + col8 * 8);
            f32x4 bb = *(const f32x4*)(ks2 + row * DD + col8 * 8 + 4);
            s16x8 h, l;
            #pragma unroll
            for (int j = 0; j < 4; ++j) {
                uint16_t hh = f2bf(a[j]);
                h[j] = (short)hh; l[j] = (short)f2bf(a[j] - bf2f(hh));
                uint16_t hb = f2bf(bb[j]);
                h[4 + j] = (short)hb; l[4 + j] = (short)f2bf(bb[j] - bf2f(hb));
            }
            *(s16x8*)(lkh + swzb(row, col8 * 16)) = h;
            *(s16x8*)(lkl + swzb(row, col8 * 16)) = l;
        }
        #pragma unroll
        for (int it = 0; it < 8; ++it) {
            int c = tid + it * 256;
            int key = c >> 5, dp = (c & 31) * 2;
            f32x2 a = *(const f32x2*)(vs + key * DD + dp);
            *(uint16_t*)(lvt + swzb(dp,     key * 2)) = f2bf(a[0]);
            *(uint16_t*)(lvt + swzb(dp + 1, key * 2)) = f2bf(a[1]);
        }
        if (tid < BK) lmask[tid] = mb[kt * BK + tid];
        __syncthreads();

        f32x4 s[4];
        #pragma unroll
        for (int f = 0; f < 4; ++f) s[f] = (f32x4){0.f, 0.f, 0.f, 0.f};
        #pragma unroll
        for (int f = 0; f < 4; ++f) {
            #pragma unroll
            for (int kc = 0; kc < 2; ++kc) {
                s16x8 kfh = *(const s16x8*)(lkh + swzb(f * 16 + lm, kc * 64 + lg * 16));
                s16x8 kfl = *(const s16x8*)(lkl + swzb(f * 16 + lm, kc * 64 + lg * 16));
                s[f] = __builtin_amdgcn_mfma_f32_16x16x32_bf16(qfh[kc], kfh, s[f], 0, 0, 0);
                s[f] = __builtin_amdgcn_mfma_f32_16x16x32_bf16(qfh[kc], kfl, s[f], 0, 0, 0);
                s[f] = __builtin_amdgcn_mfma_f32_16x16x32_bf16(qfl[kc], kfh, s[f], 0, 0, 0);
            }
        }

        float mv[4];
        #pragma unroll
        for (int f = 0; f < 4; ++f) mv[f] = lmask[f * 16 + lm];

        float pmax[4];
        #pragma unroll
        for (int i = 0; i < 4; ++i) {
            float x = -1e30f;
            #pragma unroll
            for (int f = 0; f < 4; ++f) {
                float sv = (mv[f] != 0.f) ? s[f][i] : -1e30f;
                s[f][i] = sv;
                x = fmaxf(x, sv);
            }
            #pragma unroll
            for (int off = 1; off < 16; off <<= 1)
                x = fmaxf(x, __shfl_xor(x, off, 64));
            pmax[i] = x;
        }

        float scl[4];
        #pragma unroll
        for (int i = 0; i < 4; ++i) {
            float mn = fmaxf(mrow[i], pmax[i]);
            scl[i] = __expf(mrow[i] - mn);
            mrow[i] = mn;
        }
        float rs[4] = {0.f, 0.f, 0.f, 0.f};
        #pragma unroll
        for (int f = 0; f < 4; ++f) {
            #pragma unroll
            for (int i = 0; i < 4; ++i) {
                float p = __expf(s[f][i] - mrow[i]);
                s[f][i] = p;
                rs[i] += p;
            }
        }
        #pragma unroll
        for (int i = 0; i < 4; ++i) {
            #pragma unroll
            for (int off = 1; off < 16; off <<= 1)
                rs[i] += __shfl_xor(rs[i], off, 64);
            lrow[i] = lrow[i] * scl[i] + rs[i];
        }
        #pragma unroll
        for (int d = 0; d < 4; ++d)
            #pragma unroll
            for (int i = 0; i < 4; ++i)
                oacc[d][i] *= scl[i];

        #pragma unroll
        for (int f = 0; f < 4; ++f)
            #pragma unroll
            for (int i = 0; i < 4; ++i)
                *(uint16_t*)(lpp + swzb(w * 16 + lg * 4 + i, (f * 16 + lm) * 2)) = f2bf(s[f][i]);
        __syncthreads();

        #pragma unroll
        for (int kc = 0; kc < 2; ++kc) {
            s16x8 pf = *(const s16x8*)(lpp + swzb(w * 16 + lm, kc * 64 + lg * 16));
            #pragma unroll
            for (int d = 0; d < 4; ++d) {
                s16x8 vf = *(const s16x8*)(lvt + swzb(d * 16 + lm, kc * 64 + lg * 16));
                oacc[d] = __builtin_amdgcn_mfma_f32_16x16x32_bf16(pf, vf, oacc[d], 0, 0, 0);
            }
        }
    }

    float* ob = out + ((size_t)b * SLQ + (size_t)qt * 64) * DD;
    #pragma unroll
    for (int i = 0; i < 4; ++i) {
        float inv = 1.f / (lrow[i] + 1e-13f);
        int row = w * 16 + lg * 4 + i;
        #pragma unroll
        for (int d = 0; d < 4; ++d)
            ob[row * DD + d * 16 + lm] = oacc[d][i] * inv;
    }
}

extern "C" void kernel_launch(void* const* d_in, const int* in_sizes, int n_in,
                              void* d_out, int out_size, void* d_ws, size_t ws_size,
                              hipStream_t stream) {
    const float* q  = (const float*)d_in[0];
    const float* k  = (const float*)d_in[1];
    const float* v  = (const float*)d_in[2];
    const float* vm = (const float*)d_in[3];
    float* out = (float*)d_out;

    const size_t TB     = (size_t)NB * SLK * DD * 2;          // 4 MB per fp16/bf16 tensor
    const size_t BIAS   = (size_t)NB * SLK * 4;               // 128 KB
    const size_t PL_PER = (size_t)NB * QTILES * BQ * 4;       // 512 KB per split-unit
    const size_t PO_PER = (size_t)NB * QTILES * BQ * DD * 2;  // 4 MB per split-unit (bf16)
    const size_t base = 3 * TB + BIAS;

    int nsp = 0;
    for (int c = 2; c >= 1; --c) {
        if (ws_size >= base + (size_t)c * (PL_PER + PO_PER)) { nsp = c; break; }
    }
    if (nsp == 0) {
        if (ws_size >= base) nsp = 1;   // nsp=1 needs no po/pl
        else {
            dim3 grid(SLQ / 64, NB);
            attn_fallback<<<grid, dim3(256), 0, stream>>>(q, k, v, vm, out);
            return;
        }
    }

    char*     qs    = (char*)d_ws;
    char*     ks    = qs + TB;
    char*     vts   = ks + TB;
    float*    bias2 = (float*)(vts + TB);
    float*    pl    = (float*)((char*)bias2 + BIAS);
    uint16_t* po    = (uint16_t*)((char*)pl + (size_t)nsp * PL_PER);

    prep_all<<<dim3(1664), dim3(256), 0, stream>>>(q, k, v, vm, qs, ks, vts, bias2);
    attn_fwd<<<dim3(512 * nsp), dim3(256), 0, stream>>>(qs, ks, vts, bias2, po, pl, out, nsp);
    if (nsp > 1)
        merge_k<<<dim3(NB * QTILES), dim3(256), 0, stream>>>(po, pl, out, nsp);
}